// Round 5
// baseline (314.331 us; speedup 1.0000x reference)
//
#include <hip/hip_runtime.h>

#define EPS 1e-5f
#define SLOPE 0.2f

// ---- LDS float offsets (all float4-aligned except the 7-float tail) ----
#define OW1 0
#define OW2 4096
#define OW3 6144
#define OW4 8192
#define OW5 8704
#define OW6 8832
#define OW7 8864
#define OG1 8872
#define OB1 8904
#define OG2 8936
#define OB2 9000
#define OG3 9064
#define OB3 9096
#define OG4 9128
#define OB4 9144
#define OG5 9160
#define OB5 9168
#define OG6 9176
#define OB6 9180
#define OG7 9184
#define OB7 9186
#define OW8 9188
#define OB8 9190
#define SMEM_FLOATS 9191   // 36764 B -> 36864 B block granularity -> 4 blocks/CU

// Copy-free LayerNorm + LeakyReLU over N register-resident elements.
template<int N>
__device__ __forceinline__ void ln_lrelu(float* h, const float* g, const float* b) {
  float m, v;
  if constexpr (N >= 4) {
    float s0 = 0.f, s1 = 0.f, s2 = 0.f, s3 = 0.f;
#pragma unroll
    for (int j = 0; j < N; j += 4) {
      s0 += h[j]; s1 += h[j + 1]; s2 += h[j + 2]; s3 += h[j + 3];
    }
    m = ((s0 + s1) + (s2 + s3)) * (1.0f / N);
    float v0 = 0.f, v1 = 0.f, v2 = 0.f, v3 = 0.f;
#pragma unroll
    for (int j = 0; j < N; j += 4) {
      float d0 = h[j] - m, d1 = h[j + 1] - m, d2 = h[j + 2] - m, d3 = h[j + 3] - m;
      v0 = fmaf(d0, d0, v0); v1 = fmaf(d1, d1, v1);
      v2 = fmaf(d2, d2, v2); v3 = fmaf(d3, d3, v3);
    }
    v = ((v0 + v1) + (v2 + v3)) * (1.0f / N);
  } else {
    float s = 0.f;
#pragma unroll
    for (int j = 0; j < N; ++j) s += h[j];
    m = s * (1.0f / N);
    float vv = 0.f;
#pragma unroll
    for (int j = 0; j < N; ++j) { float d = h[j] - m; vv = fmaf(d, d, vv); }
    v = vv * (1.0f / N);
  }
  float rs = rsqrtf(v + EPS);
#pragma unroll
  for (int j = 0; j < N; ++j) {
    float t = (h[j] - m) * rs * g[j] + b[j];
    h[j] = fmaxf(t, SLOPE * t);
  }
}

template<int DIN, int DOUT>
__device__ __forceinline__ void linear(const float* hin, float* hout, const float* W) {
#pragma unroll
  for (int j = 0; j < DOUT; ++j) hout[j] = 0.f;
#pragma unroll
  for (int k = 0; k < DIN; ++k) {
    float hk = hin[k];
#pragma unroll
    for (int j = 0; j < DOUT; ++j) hout[j] = fmaf(hk, W[k * DOUT + j], hout[j]);
  }
}

// Consume 16 x-columns (4 float4) against W rows (in LDS) starting at Wbase.
__device__ __forceinline__ void consume16(const float4* buf, const float* Wbase,
                                          float* h1) {
#pragma unroll
  for (int q = 0; q < 4; ++q) {
#pragma unroll
    for (int kk = 0; kk < 4; ++kk) {
      float xk = (kk == 0) ? buf[q].x : (kk == 1) ? buf[q].y
               : (kk == 2) ? buf[q].z : buf[q].w;
      const float* wr = Wbase + (q * 4 + kk) * 32;
#pragma unroll
      for (int j = 0; j < 32; ++j) h1[j] = fmaf(xk, wr[j], h1[j]);
    }
  }
}

__device__ __forceinline__ void stage4(float* dst, const float* __restrict__ src,
                                       int nf4, int tid) {
  const float4* s4 = reinterpret_cast<const float4*>(src);
  float4* d4 = reinterpret_cast<float4*>(dst);
  for (int i = tid; i < nf4; i += 256) d4[i] = s4[i];
}

__global__ __launch_bounds__(256) void disc_fused(
    const float* __restrict__ x,
    const float* __restrict__ W1, const float* __restrict__ g1, const float* __restrict__ b1,
    const float* __restrict__ W2, const float* __restrict__ g2, const float* __restrict__ b2,
    const float* __restrict__ W3, const float* __restrict__ g3, const float* __restrict__ b3,
    const float* __restrict__ W4, const float* __restrict__ g4, const float* __restrict__ b4,
    const float* __restrict__ W5, const float* __restrict__ g5, const float* __restrict__ b5,
    const float* __restrict__ W6, const float* __restrict__ g6, const float* __restrict__ b6,
    const float* __restrict__ W7, const float* __restrict__ g7, const float* __restrict__ b7,
    const float* __restrict__ W8, const float* __restrict__ b8,
    float* __restrict__ out, int nrows) {
  __shared__ __align__(16) float smem[SMEM_FLOATS];
  const int tid = threadIdx.x;

  // ---- Stage all weights + gamma/beta into LDS (once per block) ----
  stage4(smem + OW1, W1, 1024, tid);
  stage4(smem + OW2, W2, 512, tid);
  stage4(smem + OW3, W3, 512, tid);
  stage4(smem + OW4, W4, 128, tid);
  stage4(smem + OW5, W5, 32, tid);
  stage4(smem + OW6, W6, 8, tid);
  stage4(smem + OW7, W7, 2, tid);
  stage4(smem + OG1, g1, 8, tid);
  stage4(smem + OB1, b1, 8, tid);
  stage4(smem + OG2, g2, 16, tid);
  stage4(smem + OB2, b2, 16, tid);
  stage4(smem + OG3, g3, 8, tid);
  stage4(smem + OB3, b3, 8, tid);
  stage4(smem + OG4, g4, 4, tid);
  stage4(smem + OB4, b4, 4, tid);
  stage4(smem + OG5, g5, 2, tid);
  stage4(smem + OB5, b5, 2, tid);
  stage4(smem + OG6, g6, 1, tid);
  stage4(smem + OB6, b6, 1, tid);
  if (tid == 0) {
    smem[OG7 + 0] = g7[0]; smem[OG7 + 1] = g7[1];
    smem[OB7 + 0] = b7[0]; smem[OB7 + 1] = b7[1];
    smem[OW8 + 0] = W8[0]; smem[OW8 + 1] = W8[1];
    smem[OB8] = b8[0];
  }
  __syncthreads();

  const long row = (long)blockIdx.x * 256 + tid;
  if (row >= (long)nrows) return;

  // ---- Layer 1 (128->32): direct per-thread row loads, ping-pong pipelined;
  // weights read as uniform-address LDS broadcasts (conflict-free).
  const float4* __restrict__ xr4 = reinterpret_cast<const float4*>(x) + row * 32;
  float h1[32];
#pragma unroll
  for (int j = 0; j < 32; ++j) h1[j] = 0.f;

  float4 A[4], B[4];
#pragma unroll
  for (int q = 0; q < 4; ++q) A[q] = xr4[q];
#pragma unroll
  for (int q = 0; q < 4; ++q) B[q] = xr4[4 + q];

#pragma unroll 1
  for (int bb = 0; bb < 3; ++bb) {
    consume16(A, smem + OW1 + (bb * 32) * 32, h1);
#pragma unroll
    for (int q = 0; q < 4; ++q) A[q] = xr4[(2 * bb + 2) * 4 + q];
    consume16(B, smem + OW1 + (bb * 32 + 16) * 32, h1);
#pragma unroll
    for (int q = 0; q < 4; ++q) B[q] = xr4[(2 * bb + 3) * 4 + q];
  }
  consume16(A, smem + OW1 + 96 * 32, h1);
  consume16(B, smem + OW1 + 112 * 32, h1);
  ln_lrelu<32>(h1, smem + OG1, smem + OB1);

  // ---- Layer 2 (32->64): h2 register-resident (LDS cap = 4 waves/SIMD ->
  // compiler budgets ~128 VGPRs, no spill-to-reach-8-waves pathology).
  float h2[64];
  linear<32, 64>(h1, h2, smem + OW2);
  ln_lrelu<64>(h2, smem + OG2, smem + OB2);

  float h3[32];
  linear<64, 32>(h2, h3, smem + OW3);
  ln_lrelu<32>(h3, smem + OG3, smem + OB3);

  float h4[16]; linear<32, 16>(h3, h4, smem + OW4); ln_lrelu<16>(h4, smem + OG4, smem + OB4);
  float h5[8];  linear<16, 8>(h4, h5, smem + OW5);  ln_lrelu<8>(h5, smem + OG5, smem + OB5);
  float h6[4];  linear<8, 4>(h5, h6, smem + OW6);   ln_lrelu<4>(h6, smem + OG6, smem + OB6);
  float h7[2];  linear<4, 2>(h6, h7, smem + OW7);   ln_lrelu<2>(h7, smem + OG7, smem + OB7);

  out[row] = fmaf(h7[1], smem[OW8 + 1], fmaf(h7[0], smem[OW8 + 0], smem[OB8]));
}

extern "C" void kernel_launch(void* const* d_in, const int* in_sizes, int n_in,
                              void* d_out, int out_size, void* d_ws, size_t ws_size,
                              hipStream_t stream) {
  const float* x  = (const float*)d_in[0];
  const float* W1 = (const float*)d_in[1];
  const float* g1 = (const float*)d_in[2];
  const float* b1 = (const float*)d_in[3];
  const float* W2 = (const float*)d_in[4];
  const float* g2 = (const float*)d_in[5];
  const float* b2 = (const float*)d_in[6];
  const float* W3 = (const float*)d_in[7];
  const float* g3 = (const float*)d_in[8];
  const float* b3 = (const float*)d_in[9];
  const float* W4 = (const float*)d_in[10];
  const float* g4 = (const float*)d_in[11];
  const float* b4 = (const float*)d_in[12];
  const float* W5 = (const float*)d_in[13];
  const float* g5 = (const float*)d_in[14];
  const float* b5 = (const float*)d_in[15];
  const float* W6 = (const float*)d_in[16];
  const float* g6 = (const float*)d_in[17];
  const float* b6 = (const float*)d_in[18];
  const float* W7 = (const float*)d_in[19];
  const float* g7 = (const float*)d_in[20];
  const float* b7 = (const float*)d_in[21];
  const float* W8 = (const float*)d_in[22];
  const float* b8 = (const float*)d_in[23];
  float* out = (float*)d_out;

  const int nrows = in_sizes[0] / 128;          // 524288
  const int grid = (nrows + 255) / 256;         // 2048
  hipLaunchKernelGGL(disc_fused, dim3(grid), dim3(256), 0, stream,
                     x, W1, g1, b1, W2, g2, b2, W3, g3, b3, W4, g4, b4,
                     W5, g5, b5, W6, g6, b6, W7, g7, b7, W8, b8, out, nrows);
}

// Round 6
// 252.628 us; speedup vs baseline: 1.2442x; 1.2442x over previous
//
#include <hip/hip_runtime.h>

#define EPS 1e-5f
#define SLOPE 0.2f

// Dual-row LayerNorm + LeakyReLU: g/b loads and constants shared across rows,
// two independent reduction chains per step for ILP.
template<int N>
__device__ __forceinline__ void ln_lrelu2(float* __restrict__ ha, float* __restrict__ hb,
                                          const float* __restrict__ g,
                                          const float* __restrict__ b) {
  float s0 = 0.f, s1 = 0.f, t0 = 0.f, t1 = 0.f;
#pragma unroll
  for (int j = 0; j < N; j += 2) {
    s0 += ha[j]; s1 += ha[j + 1];
    t0 += hb[j]; t1 += hb[j + 1];
  }
  const float ma = (s0 + s1) * (1.0f / N);
  const float mb = (t0 + t1) * (1.0f / N);
  float u0 = 0.f, u1 = 0.f, w0 = 0.f, w1 = 0.f;
#pragma unroll
  for (int j = 0; j < N; j += 2) {
    float da0 = ha[j] - ma, da1 = ha[j + 1] - ma;
    float db0 = hb[j] - mb, db1 = hb[j + 1] - mb;
    u0 = fmaf(da0, da0, u0); u1 = fmaf(da1, da1, u1);
    w0 = fmaf(db0, db0, w0); w1 = fmaf(db1, db1, w1);
  }
  const float rsa = rsqrtf((u0 + u1) * (1.0f / N) + EPS);
  const float rsb = rsqrtf((w0 + w1) * (1.0f / N) + EPS);
#pragma unroll
  for (int j = 0; j < N; ++j) {
    float gj = g[j], bj = b[j];
    float ta = (ha[j] - ma) * rsa * gj + bj;
    float tb = (hb[j] - mb) * rsb * gj + bj;
    ha[j] = fmaxf(ta, SLOPE * ta);
    hb[j] = fmaxf(tb, SLOPE * tb);
  }
}

// Dual-row Linear: each weight element is loaded once (wave-uniform s_load)
// and feeds two independent FMA streams.
template<int DIN, int DOUT>
__device__ __forceinline__ void linear2(const float* ha, const float* hb,
                                        float* oa, float* ob,
                                        const float* __restrict__ W) {
#pragma unroll
  for (int j = 0; j < DOUT; ++j) { oa[j] = 0.f; ob[j] = 0.f; }
#pragma unroll
  for (int k = 0; k < DIN; ++k) {
    float xa = ha[k], xb = hb[k];
    const float* wr = &W[k * DOUT];
#pragma unroll
    for (int j = 0; j < DOUT; ++j) {
      float w = wr[j];
      oa[j] = fmaf(xa, w, oa[j]);
      ob[j] = fmaf(xb, w, ob[j]);
    }
  }
}

// Consume 8 x-columns (2 float4 per row, both rows) against W1 rows at Wb.
__device__ __forceinline__ void consume8x2(float4 a0, float4 a1, float4 b0, float4 b1,
                                           const float* __restrict__ Wb,
                                           float* h1a, float* h1b) {
  const float xs_a[8] = {a0.x, a0.y, a0.z, a0.w, a1.x, a1.y, a1.z, a1.w};
  const float xs_b[8] = {b0.x, b0.y, b0.z, b0.w, b1.x, b1.y, b1.z, b1.w};
#pragma unroll
  for (int kk = 0; kk < 8; ++kk) {
    float xa = xs_a[kk], xb = xs_b[kk];
    const float* wr = Wb + kk * 32;
#pragma unroll
    for (int j = 0; j < 32; ++j) {
      float w = wr[j];
      h1a[j] = fmaf(xa, w, h1a[j]);
      h1b[j] = fmaf(xb, w, h1b[j]);
    }
  }
}

__global__ __launch_bounds__(256)
__attribute__((amdgpu_waves_per_eu(2, 3)))   // cap target occupancy at 3 waves/SIMD
void disc_fused(                             // -> 170-VGPR budget, no spill-for-occupancy
    const float* __restrict__ x,
    const float* __restrict__ W1, const float* __restrict__ g1, const float* __restrict__ b1,
    const float* __restrict__ W2, const float* __restrict__ g2, const float* __restrict__ b2,
    const float* __restrict__ W3, const float* __restrict__ g3, const float* __restrict__ b3,
    const float* __restrict__ W4, const float* __restrict__ g4, const float* __restrict__ b4,
    const float* __restrict__ W5, const float* __restrict__ g5, const float* __restrict__ b5,
    const float* __restrict__ W6, const float* __restrict__ g6, const float* __restrict__ b6,
    const float* __restrict__ W7, const float* __restrict__ g7, const float* __restrict__ b7,
    const float* __restrict__ W8, const float* __restrict__ b8,
    float* __restrict__ out, int nrows) {
  const int tid = threadIdx.x;
  const long r0 = (long)blockIdx.x * 512 + tid;        // rows r0 and r0+256
  if (r0 >= (long)nrows) return;
  long r1 = r0 + 256;
  const bool w1ok = r1 < (long)nrows;
  if (!w1ok) r1 = (long)nrows - 1;

  const float4* __restrict__ xa4 = reinterpret_cast<const float4*>(x) + r0 * 32;
  const float4* __restrict__ xb4 = reinterpret_cast<const float4*>(x) + r1 * 32;

  // ---- Layer 1 (128->32), both rows, P/Q ping-pong on 8-column chunks.
  float h1a[32], h1b[32];
#pragma unroll
  for (int j = 0; j < 32; ++j) { h1a[j] = 0.f; h1b[j] = 0.f; }

  float4 PA0 = xa4[0], PA1 = xa4[1], PB0 = xb4[0], PB1 = xb4[1];
  float4 QA0, QA1, QB0, QB1;
#pragma unroll 1
  for (int cc = 0; cc < 8; ++cc) {
    const int c0 = 2 * cc, c1 = 2 * cc + 1;
    QA0 = xa4[c1 * 2 + 0]; QA1 = xa4[c1 * 2 + 1];
    QB0 = xb4[c1 * 2 + 0]; QB1 = xb4[c1 * 2 + 1];
    consume8x2(PA0, PA1, PB0, PB1, W1 + c0 * 8 * 32, h1a, h1b);
    if (cc < 7) {
      PA0 = xa4[(c1 + 1) * 2 + 0]; PA1 = xa4[(c1 + 1) * 2 + 1];
      PB0 = xb4[(c1 + 1) * 2 + 0]; PB1 = xb4[(c1 + 1) * 2 + 1];
    }
    consume8x2(QA0, QA1, QB0, QB1, W1 + c1 * 8 * 32, h1a, h1b);
  }
  ln_lrelu2<32>(h1a, h1b, g1, b1);

  // ---- Layer 2 (32->64) streamed, dual-row: h2 never register-resident.
  // Pass 1: LN stats via E[x^2]-m^2 (EPS floors the variance -> safe).
  float suma = 0.f, sqa = 0.f, sumb = 0.f, sqb = 0.f;
#pragma unroll 1
  for (int jb = 0; jb < 16; ++jb) {
    float a0 = 0.f, a1 = 0.f, a2 = 0.f, a3 = 0.f;
    float c0 = 0.f, c1 = 0.f, c2 = 0.f, c3 = 0.f;
#pragma unroll
    for (int k = 0; k < 32; ++k) {
      const float* wr = &W2[k * 64 + jb * 4];
      float w0 = wr[0], w1 = wr[1], w2 = wr[2], w3 = wr[3];
      float xa = h1a[k], xb = h1b[k];
      a0 = fmaf(xa, w0, a0); a1 = fmaf(xa, w1, a1);
      a2 = fmaf(xa, w2, a2); a3 = fmaf(xa, w3, a3);
      c0 = fmaf(xb, w0, c0); c1 = fmaf(xb, w1, c1);
      c2 = fmaf(xb, w2, c2); c3 = fmaf(xb, w3, c3);
    }
    suma += (a0 + a1) + (a2 + a3);
    sqa = fmaf(a0, a0, sqa); sqa = fmaf(a1, a1, sqa);
    sqa = fmaf(a2, a2, sqa); sqa = fmaf(a3, a3, sqa);
    sumb += (c0 + c1) + (c2 + c3);
    sqb = fmaf(c0, c0, sqb); sqb = fmaf(c1, c1, sqb);
    sqb = fmaf(c2, c2, sqb); sqb = fmaf(c3, c3, sqb);
  }
  const float m2a = suma * (1.0f / 64.0f);
  const float v2a = fmaf(-m2a, m2a, sqa * (1.0f / 64.0f));
  const float rs2a = rsqrtf(v2a + EPS);
  const float m2b = sumb * (1.0f / 64.0f);
  const float v2b = fmaf(-m2b, m2b, sqb * (1.0f / 64.0f));
  const float rs2b = rsqrtf(v2b + EPS);

  // Pass 2: recompute h2 block, LN+LeakyReLU, fuse into h3 accumulation.
  float h3a[32], h3b[32];
#pragma unroll
  for (int i = 0; i < 32; ++i) { h3a[i] = 0.f; h3b[i] = 0.f; }
#pragma unroll 1
  for (int jb = 0; jb < 16; ++jb) {
    float a0 = 0.f, a1 = 0.f, a2 = 0.f, a3 = 0.f;
    float c0 = 0.f, c1 = 0.f, c2 = 0.f, c3 = 0.f;
#pragma unroll
    for (int k = 0; k < 32; ++k) {
      const float* wr = &W2[k * 64 + jb * 4];
      float w0 = wr[0], w1 = wr[1], w2 = wr[2], w3 = wr[3];
      float xa = h1a[k], xb = h1b[k];
      a0 = fmaf(xa, w0, a0); a1 = fmaf(xa, w1, a1);
      a2 = fmaf(xa, w2, a2); a3 = fmaf(xa, w3, a3);
      c0 = fmaf(xb, w0, c0); c1 = fmaf(xb, w1, c1);
      c2 = fmaf(xb, w2, c2); c3 = fmaf(xb, w3, c3);
    }
#pragma unroll
    for (int u = 0; u < 4; ++u) {
      float av = (u == 0) ? a0 : (u == 1) ? a1 : (u == 2) ? a2 : a3;
      float cv = (u == 0) ? c0 : (u == 1) ? c1 : (u == 2) ? c2 : c3;
      int j = jb * 4 + u;
      float gj = g2[j], bj = b2[j];
      float ya = (av - m2a) * rs2a * gj + bj;
      float yb = (cv - m2b) * rs2b * gj + bj;
      ya = fmaxf(ya, SLOPE * ya);
      yb = fmaxf(yb, SLOPE * yb);
      const float* wr3 = &W3[j * 32];
#pragma unroll
      for (int i = 0; i < 32; ++i) {
        float w = wr3[i];
        h3a[i] = fmaf(ya, w, h3a[i]);
        h3b[i] = fmaf(yb, w, h3b[i]);
      }
    }
  }
  ln_lrelu2<32>(h3a, h3b, g3, b3);

  float h4a[16], h4b[16];
  linear2<32, 16>(h3a, h3b, h4a, h4b, W4); ln_lrelu2<16>(h4a, h4b, g4, b4);
  float h5a[8], h5b[8];
  linear2<16, 8>(h4a, h4b, h5a, h5b, W5);  ln_lrelu2<8>(h5a, h5b, g5, b5);
  float h6a[4], h6b[4];
  linear2<8, 4>(h5a, h5b, h6a, h6b, W6);   ln_lrelu2<4>(h6a, h6b, g6, b6);
  float h7a[2], h7b[2];
  linear2<4, 2>(h6a, h6b, h7a, h7b, W7);   ln_lrelu2<2>(h7a, h7b, g7, b7);

  const float w80 = W8[0], w81 = W8[1], bb8 = b8[0];
  out[r0] = fmaf(h7a[1], w81, fmaf(h7a[0], w80, bb8));
  if (w1ok) out[r1] = fmaf(h7b[1], w81, fmaf(h7b[0], w80, bb8));
}

extern "C" void kernel_launch(void* const* d_in, const int* in_sizes, int n_in,
                              void* d_out, int out_size, void* d_ws, size_t ws_size,
                              hipStream_t stream) {
  const float* x  = (const float*)d_in[0];
  const float* W1 = (const float*)d_in[1];
  const float* g1 = (const float*)d_in[2];
  const float* b1 = (const float*)d_in[3];
  const float* W2 = (const float*)d_in[4];
  const float* g2 = (const float*)d_in[5];
  const float* b2 = (const float*)d_in[6];
  const float* W3 = (const float*)d_in[7];
  const float* g3 = (const float*)d_in[8];
  const float* b3 = (const float*)d_in[9];
  const float* W4 = (const float*)d_in[10];
  const float* g4 = (const float*)d_in[11];
  const float* b4 = (const float*)d_in[12];
  const float* W5 = (const float*)d_in[13];
  const float* g5 = (const float*)d_in[14];
  const float* b5 = (const float*)d_in[15];
  const float* W6 = (const float*)d_in[16];
  const float* g6 = (const float*)d_in[17];
  const float* b6 = (const float*)d_in[18];
  const float* W7 = (const float*)d_in[19];
  const float* g7 = (const float*)d_in[20];
  const float* b7 = (const float*)d_in[21];
  const float* W8 = (const float*)d_in[22];
  const float* b8 = (const float*)d_in[23];
  float* out = (float*)d_out;

  const int nrows = in_sizes[0] / 128;            // 524288
  const int grid = (nrows + 511) / 512;           // 1024 blocks x 2 rows/thread
  hipLaunchKernelGGL(disc_fused, dim3(grid), dim3(256), 0, stream,
                     x, W1, g1, b1, W2, g2, b2, W3, g3, b3, W4, g4, b4,
                     W5, g5, b5, W6, g6, b6, W7, g7, b7, W8, b8, out, nrows);
}